// Round 1
// 484.744 us; speedup vs baseline: 1.0265x; 1.0265x over previous
//
#include <hip/hip_runtime.h>

#define BB 2
#define LL 512
#define DIM 128
#define KK 32
#define EPSF 1e-5f

// ---------------------------------------------------------------------------
// Kernel A: per (path, b, q) row:
//   path 0: out_mean[b,q,:] -> out_agg = mean@W_out+b_out -> go = out_agg@Wg_o
//   path 1: in_mean [b,q,:] -> in_agg  = mean@W_in +b_in  -> gi = in_agg @Wg_i
// grid = 2*B*L blocks, 128 threads. Results stored f32 in workspace.
// ---------------------------------------------------------------------------
__global__ __launch_bounds__(DIM) void agg_gemm_kernel(
    const float* __restrict__ pair,
    const float* __restrict__ W_out, const float* __restrict__ b_out,
    const float* __restrict__ W_in,  const float* __restrict__ b_in,
    const float* __restrict__ W_g,
    float* __restrict__ agg,    // [2][B*L][DIM]  (0=out_agg, 1=in_agg)
    float* __restrict__ gpart)  // [2][B*L][DIM]  (0=go,      1=gi)
{
    const int t    = threadIdx.x;
    const int bid  = blockIdx.x;          // [0, 2*B*L)
    const int path = bid >> 10;           // B*L = 1024
    const int r    = bid & 1023;          // b*L + q
    const int b    = r >> 9;              // L = 512
    const int q    = r & 511;

    __shared__ float sm[DIM];

    // ---- stage 0: mean over K sampled positions (idx[k] = (k*511)/31) ----
    // Compile-time strides per path so address math folds to immediates.
    float acc = 0.f;
    if (path == 0) {
        const float* base = pair + ((long)(b * LL + q) * LL) * DIM + t;
#pragma unroll
        for (int k = 0; k < KK; ++k) {
            const int jj = (k * (LL - 1)) / (KK - 1);   // exact floor(linspace)
            acc += base[(long)jj * DIM];
        }
    } else {
        const float* base = pair + (long)b * LL * LL * DIM + (long)q * DIM + t;
#pragma unroll
        for (int k = 0; k < KK; ++k) {
            const int jj = (k * (LL - 1)) / (KK - 1);
            acc += base[(long)jj * (LL * DIM)];
        }
    }
    sm[t] = acc * (1.0f / KK);
    __syncthreads();

    // ---- stage 1: agg = mean @ W + bias ----
    const float* W    = (path == 0) ? W_out : W_in;
    const float* bias = (path == 0) ? b_out : b_in;
    float a = bias[t];
#pragma unroll 8
    for (int k = 0; k < DIM; ++k)
        a += sm[k] * W[k * DIM + t];
    __syncthreads();              // everyone done reading sm before overwrite
    sm[t] = a;
    agg[(long)path * BB * LL * DIM + (long)r * DIM + t] = a;
    __syncthreads();

    // ---- stage 2: gpart = agg @ Wg_path (b_g added elementwise later) ----
    const float* Wg = W_g + path * DIM * DIM;
    float g = 0.f;
#pragma unroll 8
    for (int k = 0; k < DIM; ++k)
        g += sm[k] * Wg[k * DIM + t];
    gpart[(long)path * BB * LL * DIM + (long)r * DIM + t] = g;
}

// ---------------------------------------------------------------------------
// Kernel B v2: gate/blend + LayerNorm over DIM=128.
// One block per (b, i, half): 256 threads = 16 j-rows x 16 lanes, looping
// 16 j-tiles (256 j values per block). Row-invariant streams (go, out_agg)
// and element-invariant streams (b_g, ln_w, ln_b) are loaded ONCE per block
// into registers; per row only pair/gi/in_agg are loaded (3x512B read +
// 512B write vs the previous 9x512B read).
// Element mapping: lane16 owns floats [4*l,4*l+4) and [64+4*l,64+4*l+4)
// -> both float4 loads are fully coalesced 256B segments per 16-lane group.
// ---------------------------------------------------------------------------
__device__ __forceinline__ void load8c(const float* __restrict__ base,
                                       int e0, int e1, float* f) {
    const float4 a = *reinterpret_cast<const float4*>(base + e0);
    const float4 b = *reinterpret_cast<const float4*>(base + e1);
    f[0] = a.x; f[1] = a.y; f[2] = a.z; f[3] = a.w;
    f[4] = b.x; f[5] = b.y; f[6] = b.z; f[7] = b.w;
}

__global__ __launch_bounds__(256, 4) void fuse_ln_kernel(
    const float* __restrict__ pair,
    const float* __restrict__ out_agg, const float* __restrict__ in_agg,
    const float* __restrict__ go,      const float* __restrict__ gi,
    const float* __restrict__ b_g, const float* __restrict__ ln_w,
    const float* __restrict__ ln_b,
    float* __restrict__ out)
{
    const int tid    = threadIdx.x;
    const int lane16 = tid & 15;
    const int rloc   = tid >> 4;               // 0..15: j offset inside tile
    const int blk    = blockIdx.x;             // [0, 2*B*L)
    const int half   = blk & 1;
    const int bi     = blk >> 1;               // b*L + i
    const int b      = bi >> 9;
    const int jbase  = half * (LL / 2);

    const int e0 = lane16 * 4;                 // floats [e0, e0+4)
    const int e1 = 64 + lane16 * 4;            // floats [e1, e1+4)

    // ---- block-invariant data -> registers (loaded once) ----
    float gof[8], oaf[8], bg[8], lw[8], lb[8];
    load8c(go      + (long)bi * DIM, e0, e1, gof);
    load8c(out_agg + (long)bi * DIM, e0, e1, oaf);
    load8c(b_g,  e0, e1, bg);
    load8c(ln_w, e0, e1, lw);
    load8c(ln_b, e0, e1, lb);

    const long bL = (long)b * LL;

#pragma unroll 2
    for (int jt = 0; jt < (LL / 2) / 16; ++jt) {
        const int  j   = jbase + jt * 16 + rloc;
        const long row = (long)bi * LL + j;    // (b*L+i)*L + j
        const long bj  = bL + j;

        float p[8], gif[8], iaf[8];
        load8c(pair   + row * DIM, e0, e1, p);
        load8c(gi     + bj  * DIM, e0, e1, gif);
        load8c(in_agg + bj  * DIM, e0, e1, iaf);

        float x[8];
        float sum = 0.f, ss = 0.f;
#pragma unroll
        for (int c = 0; c < 8; ++c) {
            const float z    = gof[c] + gif[c] + bg[c];
            const float e    = __builtin_amdgcn_exp2f(z * -1.442695041f);
            const float gate = __builtin_amdgcn_rcpf(1.0f + e);
            const float u    = oaf[c] + iaf[c];
            const float xv   = p[c] + gate * (u - p[c]);
            x[c] = xv;
            sum += xv;
            ss  += xv * xv;
        }

        // reduce across the 16 lanes of this row (xor masks stay in-group)
#pragma unroll
        for (int m = 1; m < 16; m <<= 1) {
            sum += __shfl_xor(sum, m);
            ss  += __shfl_xor(ss,  m);
        }
        const float mu   = sum * (1.0f / DIM);
        const float var  = ss * (1.0f / DIM) - mu * mu;
        const float rstd = rsqrtf(var + EPSF);

        float y[8];
#pragma unroll
        for (int c = 0; c < 8; ++c)
            y[c] = (x[c] - mu) * rstd * lw[c] + lb[c];

        float* op = out + row * DIM;
        *reinterpret_cast<float4*>(op + e0) = make_float4(y[0], y[1], y[2], y[3]);
        *reinterpret_cast<float4*>(op + e1) = make_float4(y[4], y[5], y[6], y[7]);
    }
}

extern "C" void kernel_launch(void* const* d_in, const int* in_sizes, int n_in,
                              void* d_out, int out_size, void* d_ws, size_t ws_size,
                              hipStream_t stream) {
    const float* pair  = (const float*)d_in[0];
    const float* W_out = (const float*)d_in[1];
    const float* b_out = (const float*)d_in[2];
    const float* W_in  = (const float*)d_in[3];
    const float* b_in  = (const float*)d_in[4];
    const float* W_g   = (const float*)d_in[5];
    const float* b_g   = (const float*)d_in[6];
    const float* ln_w  = (const float*)d_in[7];
    const float* ln_b  = (const float*)d_in[8];
    float* out = (float*)d_out;

    float* agg   = (float*)d_ws;                     // 2*1024*128 f32 = 1 MB
    float* gpart = agg + 2 * BB * LL * DIM;          // 1 MB more

    agg_gemm_kernel<<<2 * BB * LL, DIM, 0, stream>>>(
        pair, W_out, b_out, W_in, b_in, W_g, agg, gpart);

    fuse_ln_kernel<<<2 * BB * LL, 256, 0, stream>>>(
        pair,
        agg,   agg   + BB * LL * DIM,
        gpart, gpart + BB * LL * DIM,
        b_g, ln_w, ln_b, out);
}

// Round 2
// 480.965 us; speedup vs baseline: 1.0346x; 1.0079x over previous
//
#include <hip/hip_runtime.h>

#define BB 2
#define LL 512
#define DIM 128
#define KK 32
#define EPSF 1e-5f

typedef float f32x4 __attribute__((ext_vector_type(4)));

// ---------------------------------------------------------------------------
// Kernel A: per (path, b, q) row:
//   path 0: out_mean -> out_agg(=oa) -> go ; packed into bipack[r] = [go|oa]
//   path 1: in_mean  -> in_agg (=ia) -> gi ; packed into bjpack[r] = [gi|ia]
// grid = 2*B*L blocks, 128 threads. Packed rows are 256 floats = 1 KB,
// so kernel B reads ONE contiguous 1 KB chunk per j instead of two streams
// 512 KB apart.
// ---------------------------------------------------------------------------
__global__ __launch_bounds__(DIM) void agg_gemm_kernel(
    const float* __restrict__ pair,
    const float* __restrict__ W_out, const float* __restrict__ b_out,
    const float* __restrict__ W_in,  const float* __restrict__ b_in,
    const float* __restrict__ W_g,
    float* __restrict__ bipack,   // [B*L][256]  (go | oa)
    float* __restrict__ bjpack)   // [B*L][256]  (gi | ia)
{
    const int t    = threadIdx.x;
    const int bid  = blockIdx.x;          // [0, 2*B*L)
    const int path = bid >> 10;           // B*L = 1024
    const int r    = bid & 1023;          // b*L + q
    const int b    = r >> 9;              // L = 512
    const int q    = r & 511;

    __shared__ float sm[DIM];

    // ---- stage 0: mean over K sampled positions (idx[k] = (k*511)/31) ----
    float acc = 0.f;
    if (path == 0) {
        const float* base = pair + ((long)(b * LL + q) * LL) * DIM + t;
#pragma unroll
        for (int k = 0; k < KK; ++k) {
            const int jj = (k * (LL - 1)) / (KK - 1);   // exact floor(linspace)
            acc += base[(long)jj * DIM];
        }
    } else {
        const float* base = pair + (long)b * LL * LL * DIM + (long)q * DIM + t;
#pragma unroll
        for (int k = 0; k < KK; ++k) {
            const int jj = (k * (LL - 1)) / (KK - 1);
            acc += base[(long)jj * (LL * DIM)];
        }
    }
    sm[t] = acc * (1.0f / KK);
    __syncthreads();

    float* pk = (path == 0 ? bipack : bjpack) + (long)r * 256;

    // ---- stage 1: agg = mean @ W + bias  -> pk[128+t] ----
    const float* W    = (path == 0) ? W_out : W_in;
    const float* bias = (path == 0) ? b_out : b_in;
    float a = bias[t];
#pragma unroll 8
    for (int k = 0; k < DIM; ++k)
        a += sm[k] * W[k * DIM + t];
    __syncthreads();              // everyone done reading sm before overwrite
    sm[t] = a;
    pk[128 + t] = a;
    __syncthreads();

    // ---- stage 2: gpart = agg @ Wg_path -> pk[t] ----
    const float* Wg = W_g + path * DIM * DIM;
    float g = 0.f;
#pragma unroll 8
    for (int k = 0; k < DIM; ++k)
        g += sm[k] * Wg[k * DIM + t];
    pk[t] = g;
}

// ---------------------------------------------------------------------------
// Kernel B v3: gate/blend + LayerNorm over DIM=128.
// 32 lanes per row x 4 floats/lane: every stream is ONE fully-contiguous
// 512 B access per row (4 vector-mem ops/row total vs 8 in v2).
// One block per (b, i, half): 256 threads = 8 j-rows/iter x 32 iters.
// Block-invariant [go|oa] + b_g/ln_w/ln_b live in registers; go+b_g folded.
// pair loads and out stores are nontemporal (no reuse) to keep L2 for the
// packed agg tables.
// ---------------------------------------------------------------------------
__global__ __launch_bounds__(256) void fuse_ln_kernel(
    const float* __restrict__ pair,
    const float* __restrict__ bipack, const float* __restrict__ bjpack,
    const float* __restrict__ b_g, const float* __restrict__ ln_w,
    const float* __restrict__ ln_b,
    float* __restrict__ out)
{
    const int tid  = threadIdx.x;
    const int l32  = tid & 31;
    const int rloc = tid >> 5;                 // 0..7: j offset inside tile
    const int blk  = blockIdx.x;               // [0, 2*B*L)
    const int half = blk & 1;
    const int bi   = blk >> 1;                 // b*L + i
    const int b    = bi >> 9;
    const int jbase = half * (LL / 2);
    const int e    = l32 * 4;                  // floats [e, e+4)

    // ---- block-invariant data -> registers (loaded once) ----
    const f32x4 go4 = *reinterpret_cast<const f32x4*>(bipack + (long)bi * 256 + e);
    const f32x4 oa4 = *reinterpret_cast<const f32x4*>(bipack + (long)bi * 256 + 128 + e);
    const f32x4 bg4 = *reinterpret_cast<const f32x4*>(b_g  + e);
    const f32x4 lw4 = *reinterpret_cast<const f32x4*>(ln_w + e);
    const f32x4 lb4 = *reinterpret_cast<const f32x4*>(ln_b + e);
    const f32x4 zc4 = go4 + bg4;               // fold bias into go once

    const long bL = (long)b * LL;

#pragma unroll 2
    for (int it = 0; it < (LL / 2) / 8; ++it) {
        const int  j   = jbase + it * 8 + rloc;
        const long row = (long)bi * LL + j;    // (b*L+i)*L + j
        const long bj  = bL + j;

        const f32x4 pv = __builtin_nontemporal_load(
            reinterpret_cast<const f32x4*>(pair + row * DIM + e));
        const f32x4 gv = *reinterpret_cast<const f32x4*>(bjpack + bj * 256 + e);
        const f32x4 iv = *reinterpret_cast<const f32x4*>(bjpack + bj * 256 + 128 + e);

        f32x4 x;
        float sum = 0.f, ss = 0.f;
#pragma unroll
        for (int c = 0; c < 4; ++c) {
            const float z    = zc4[c] + gv[c];
            const float ex   = __builtin_amdgcn_exp2f(z * -1.442695041f);
            const float gate = __builtin_amdgcn_rcpf(1.0f + ex);
            const float u    = oa4[c] + iv[c];
            const float xv   = pv[c] + gate * (u - pv[c]);
            x[c] = xv;
            sum += xv;
            ss  += xv * xv;
        }

        // reduce across the 32 lanes of this row (xor masks stay in-group)
#pragma unroll
        for (int m = 1; m < 32; m <<= 1) {
            sum += __shfl_xor(sum, m);
            ss  += __shfl_xor(ss,  m);
        }
        const float mu   = sum * (1.0f / DIM);
        const float var  = ss * (1.0f / DIM) - mu * mu;
        const float rstd = rsqrtf(var + EPSF);

        f32x4 y;
#pragma unroll
        for (int c = 0; c < 4; ++c)
            y[c] = (x[c] - mu) * rstd * lw4[c] + lb4[c];

        __builtin_nontemporal_store(
            y, reinterpret_cast<f32x4*>(out + row * DIM + e));
    }
}

extern "C" void kernel_launch(void* const* d_in, const int* in_sizes, int n_in,
                              void* d_out, int out_size, void* d_ws, size_t ws_size,
                              hipStream_t stream) {
    const float* pair  = (const float*)d_in[0];
    const float* W_out = (const float*)d_in[1];
    const float* b_out = (const float*)d_in[2];
    const float* W_in  = (const float*)d_in[3];
    const float* b_in  = (const float*)d_in[4];
    const float* W_g   = (const float*)d_in[5];
    const float* b_g   = (const float*)d_in[6];
    const float* ln_w  = (const float*)d_in[7];
    const float* ln_b  = (const float*)d_in[8];
    float* out = (float*)d_out;

    float* bipack = (float*)d_ws;                    // 1024*256 f32 = 1 MB
    float* bjpack = bipack + BB * LL * 256;          // 1 MB more

    agg_gemm_kernel<<<2 * BB * LL, DIM, 0, stream>>>(
        pair, W_out, b_out, W_in, b_in, W_g, bipack, bjpack);

    fuse_ln_kernel<<<2 * BB * LL, 256, 0, stream>>>(
        pair, bipack, bjpack, b_g, ln_w, ln_b, out);
}

// Round 3
// 480.461 us; speedup vs baseline: 1.0357x; 1.0010x over previous
//
#include <hip/hip_runtime.h>

#define BB 2
#define LL 512
#define DIM 128
#define KK 32
#define EPSF 1e-5f

typedef float f32x4 __attribute__((ext_vector_type(4)));

// ---------------------------------------------------------------------------
// Kernel A: per (path, b, q) row:
//   path 0: out_mean -> out_agg(=oa) -> go ; packed into bipack[r] = [go|oa]
//   path 1: in_mean  -> in_agg (=ia) -> gi ; packed into bjpack[r] = [gi|ia]
// grid = 2*B*L blocks, 128 threads. Packed rows are 256 floats = 1 KB,
// so kernel B reads ONE contiguous 1 KB chunk per j instead of two streams
// 512 KB apart.
// ---------------------------------------------------------------------------
__global__ __launch_bounds__(DIM) void agg_gemm_kernel(
    const float* __restrict__ pair,
    const float* __restrict__ W_out, const float* __restrict__ b_out,
    const float* __restrict__ W_in,  const float* __restrict__ b_in,
    const float* __restrict__ W_g,
    float* __restrict__ bipack,   // [B*L][256]  (go | oa)
    float* __restrict__ bjpack)   // [B*L][256]  (gi | ia)
{
    const int t    = threadIdx.x;
    const int bid  = blockIdx.x;          // [0, 2*B*L)
    const int path = bid >> 10;           // B*L = 1024
    const int r    = bid & 1023;          // b*L + q
    const int b    = r >> 9;              // L = 512
    const int q    = r & 511;

    __shared__ float sm[DIM];

    // ---- stage 0: mean over K sampled positions (idx[k] = (k*511)/31) ----
    float acc = 0.f;
    if (path == 0) {
        const float* base = pair + ((long)(b * LL + q) * LL) * DIM + t;
#pragma unroll
        for (int k = 0; k < KK; ++k) {
            const int jj = (k * (LL - 1)) / (KK - 1);   // exact floor(linspace)
            acc += base[(long)jj * DIM];
        }
    } else {
        const float* base = pair + (long)b * LL * LL * DIM + (long)q * DIM + t;
#pragma unroll
        for (int k = 0; k < KK; ++k) {
            const int jj = (k * (LL - 1)) / (KK - 1);
            acc += base[(long)jj * (LL * DIM)];
        }
    }
    sm[t] = acc * (1.0f / KK);
    __syncthreads();

    float* pk = (path == 0 ? bipack : bjpack) + (long)r * 256;

    // ---- stage 1: agg = mean @ W + bias  -> pk[128+t] ----
    const float* W    = (path == 0) ? W_out : W_in;
    const float* bias = (path == 0) ? b_out : b_in;
    float a = bias[t];
#pragma unroll 8
    for (int k = 0; k < DIM; ++k)
        a += sm[k] * W[k * DIM + t];
    __syncthreads();              // everyone done reading sm before overwrite
    sm[t] = a;
    pk[128 + t] = a;
    __syncthreads();

    // ---- stage 2: gpart = agg @ Wg_path -> pk[t] ----
    const float* Wg = W_g + path * DIM * DIM;
    float g = 0.f;
#pragma unroll 8
    for (int k = 0; k < DIM; ++k)
        g += sm[k] * Wg[k * DIM + t];
    pk[t] = g;
}

// ---------------------------------------------------------------------------
// Kernel B v4: gate/blend + LayerNorm over DIM=128.
// 32 lanes per row x 4 floats/lane; one block per (b, i, half); 256 threads
// = 8 j-rows/iter x 32 iters. v4 adds:
//   - explicit 1-deep software pipeline: next-j loads issued before current-j
//     compute, so VMEM is in flight during the 10-op shuffle-reduce chain
//   - __launch_bounds__(256, 8): pin 8 blocks/CU (32 waves/CU) for TLP
//   - v_rsq_f32 instead of precise rsqrt expansion
// Block-invariant [go|oa] + b_g/ln_w/ln_b in registers; go+b_g folded.
// ---------------------------------------------------------------------------
__global__ __launch_bounds__(256, 8) void fuse_ln_kernel(
    const float* __restrict__ pair,
    const float* __restrict__ bipack, const float* __restrict__ bjpack,
    const float* __restrict__ b_g, const float* __restrict__ ln_w,
    const float* __restrict__ ln_b,
    float* __restrict__ out)
{
    const int tid  = threadIdx.x;
    const int l32  = tid & 31;
    const int rloc = tid >> 5;                 // 0..7: j offset inside tile
    const int blk  = blockIdx.x;               // [0, 2*B*L)
    const int half = blk & 1;
    const int bi   = blk >> 1;                 // b*L + i
    const int b    = bi >> 9;
    const int jbase = half * (LL / 2);
    const int e    = l32 * 4;                  // floats [e, e+4)

    // ---- block-invariant data -> registers (loaded once) ----
    const f32x4 go4 = *reinterpret_cast<const f32x4*>(bipack + (long)bi * 256 + e);
    const f32x4 oa4 = *reinterpret_cast<const f32x4*>(bipack + (long)bi * 256 + 128 + e);
    const f32x4 bg4 = *reinterpret_cast<const f32x4*>(b_g  + e);
    const f32x4 lw4 = *reinterpret_cast<const f32x4*>(ln_w + e);
    const f32x4 lb4 = *reinterpret_cast<const f32x4*>(ln_b + e);
    const f32x4 zc4 = go4 + bg4;               // fold bias into go once

    const long row0 = (long)bi * LL + jbase + rloc;   // j stride is 8
    const long bj0  = (long)b * LL + jbase + rloc;

    // ---- prologue: load iteration 0 ----
    f32x4 pv = __builtin_nontemporal_load(
        reinterpret_cast<const f32x4*>(pair + row0 * DIM + e));
    f32x4 gv = *reinterpret_cast<const f32x4*>(bjpack + bj0 * 256 + e);
    f32x4 iv = *reinterpret_cast<const f32x4*>(bjpack + bj0 * 256 + 128 + e);

    constexpr int NIT = (LL / 2) / 8;          // 32 iterations
    for (int it = 0; it < NIT; ++it) {
        const long row = row0 + (long)it * 8;

        // ---- prefetch next iteration while this one computes ----
        f32x4 pvn, gvn, ivn;
        if (it + 1 < NIT) {
            const long rown = row + 8;
            const long bjn  = bj0 + (long)(it + 1) * 8;
            pvn = __builtin_nontemporal_load(
                reinterpret_cast<const f32x4*>(pair + rown * DIM + e));
            gvn = *reinterpret_cast<const f32x4*>(bjpack + bjn * 256 + e);
            ivn = *reinterpret_cast<const f32x4*>(bjpack + bjn * 256 + 128 + e);
        }

        f32x4 x;
        float sum = 0.f, ss = 0.f;
#pragma unroll
        for (int c = 0; c < 4; ++c) {
            const float z    = zc4[c] + gv[c];
            const float ex   = __builtin_amdgcn_exp2f(z * -1.442695041f);
            const float gate = __builtin_amdgcn_rcpf(1.0f + ex);
            const float u    = oa4[c] + iv[c];
            const float xv   = pv[c] + gate * (u - pv[c]);
            x[c] = xv;
            sum += xv;
            ss  += xv * xv;
        }

        // reduce across the 32 lanes of this row (xor masks stay in-group);
        // prefetched loads for it+1 are in flight during this serial chain
#pragma unroll
        for (int m = 1; m < 32; m <<= 1) {
            sum += __shfl_xor(sum, m);
            ss  += __shfl_xor(ss,  m);
        }
        const float mu   = sum * (1.0f / DIM);
        const float var  = ss * (1.0f / DIM) - mu * mu;
        const float rstd = __builtin_amdgcn_rsqf(var + EPSF);

        f32x4 y;
#pragma unroll
        for (int c = 0; c < 4; ++c)
            y[c] = (x[c] - mu) * rstd * lw4[c] + lb4[c];

        __builtin_nontemporal_store(
            y, reinterpret_cast<f32x4*>(out + row * DIM + e));

        pv = pvn; gv = gvn; iv = ivn;
    }
}

extern "C" void kernel_launch(void* const* d_in, const int* in_sizes, int n_in,
                              void* d_out, int out_size, void* d_ws, size_t ws_size,
                              hipStream_t stream) {
    const float* pair  = (const float*)d_in[0];
    const float* W_out = (const float*)d_in[1];
    const float* b_out = (const float*)d_in[2];
    const float* W_in  = (const float*)d_in[3];
    const float* b_in  = (const float*)d_in[4];
    const float* W_g   = (const float*)d_in[5];
    const float* b_g   = (const float*)d_in[6];
    const float* ln_w  = (const float*)d_in[7];
    const float* ln_b  = (const float*)d_in[8];
    float* out = (float*)d_out;

    float* bipack = (float*)d_ws;                    // 1024*256 f32 = 1 MB
    float* bjpack = bipack + BB * LL * 256;          // 1 MB more

    agg_gemm_kernel<<<2 * BB * LL, DIM, 0, stream>>>(
        pair, W_out, b_out, W_in, b_in, W_g, bipack, bjpack);

    fuse_ln_kernel<<<2 * BB * LL, 256, 0, stream>>>(
        pair, bipack, bjpack, b_g, ln_w, ln_b, out);
}